// Round 1
// baseline (54.146 us; speedup 1.0000x reference)
//
#include <hip/hip_runtime.h>

#define BB 4
#define NN 4096
#define DD 128

// Kernel 1: per-row projections. One wave (64 lanes) per row; lane l covers
// dims l and l+64. s_i[r] = dot(x[r], a[0:128]), s_j[r] = dot(x[r], a[128:256]).
__global__ __launch_bounds__(256) void score_kernel(const float* __restrict__ x,
                                                    const float* __restrict__ a,
                                                    float* __restrict__ si,
                                                    float* __restrict__ sj) {
    int wave = threadIdx.x >> 6;
    int lane = threadIdx.x & 63;
    int row  = blockIdx.x * 4 + wave;   // grid covers B*N rows exactly
    const float* xr = x + (size_t)row * DD;
    float x0 = xr[lane];
    float x1 = xr[lane + 64];
    float d1 = x0 * a[lane]      + x1 * a[lane + 64];
    float d2 = x0 * a[DD + lane] + x1 * a[DD + lane + 64];
    #pragma unroll
    for (int off = 32; off > 0; off >>= 1) {
        d1 += __shfl_down(d1, off, 64);
        d2 += __shfl_down(d2, off, 64);
    }
    if (lane == 0) {
        si[row] = d1;
        sj[row] = d2;
    }
}

// Kernel 2: one block per output row (b,i). Stage s_j[batch] in LDS,
// stable softmax over j of leaky_relu(s_i + s_j), coalesced float4 writes.
__global__ __launch_bounds__(256) void softmax_kernel(const float* __restrict__ si_g,
                                                      const float* __restrict__ sj_g,
                                                      float* __restrict__ out) {
    __shared__ float sj[NN];      // 16 KB
    __shared__ float red[4];

    const int b   = blockIdx.x >> 12;        // N = 4096 = 2^12
    const int i   = blockIdx.x & (NN - 1);
    const int tid = threadIdx.x;

    // Stage s_j for this batch; track local max while loading.
    const float* sjb = sj_g + b * NN;
    float lmax = -INFINITY;
    #pragma unroll
    for (int k = 0; k < NN / 256; ++k) {
        float v = sjb[tid + k * 256];
        sj[tid + k * 256] = v;
        lmax = fmaxf(lmax, v);
    }
    #pragma unroll
    for (int off = 32; off > 0; off >>= 1)
        lmax = fmaxf(lmax, __shfl_down(lmax, off, 64));
    if ((tid & 63) == 0) red[tid >> 6] = lmax;
    __syncthreads();
    const float sjmax = fmaxf(fmaxf(red[0], red[1]), fmaxf(red[2], red[3]));

    const float sival = si_g[b * NN + i];
    // leaky_relu is monotone increasing -> row max = leaky(s_i + max_j s_j)
    float m = sival + sjmax;
    m = m > 0.f ? m : 0.2f * m;

    // exp computed ONCE per element, kept in registers for the write pass.
    float p[16];
    float lsum = 0.f;
    #pragma unroll
    for (int g = 0; g < 4; ++g) {
        const int j0 = g * 1024 + tid * 4;
        #pragma unroll
        for (int k = 0; k < 4; ++k) {
            float e = sival + sj[j0 + k];
            e = e > 0.f ? e : 0.2f * e;
            float pv = __expf(e - m);     // e - m <= 0, exp <= 1
            p[g * 4 + k] = pv;
            lsum += pv;
        }
    }
    #pragma unroll
    for (int off = 32; off > 0; off >>= 1)
        lsum += __shfl_down(lsum, off, 64);
    __syncthreads();                      // everyone done reading red (max)
    if ((tid & 63) == 0) red[tid >> 6] = lsum;
    __syncthreads();
    const float inv = 1.f / (red[0] + red[1] + red[2] + red[3]);

    float* orow = out + (size_t)(b * NN + i) * NN;
    #pragma unroll
    for (int g = 0; g < 4; ++g) {
        const int j0 = g * 1024 + tid * 4;
        float4 v = make_float4(p[g * 4 + 0] * inv, p[g * 4 + 1] * inv,
                               p[g * 4 + 2] * inv, p[g * 4 + 3] * inv);
        *reinterpret_cast<float4*>(orow + j0) = v;
    }
}

extern "C" void kernel_launch(void* const* d_in, const int* in_sizes, int n_in,
                              void* d_out, int out_size, void* d_ws, size_t ws_size,
                              hipStream_t stream) {
    const float* x = (const float*)d_in[0];
    const float* a = (const float*)d_in[1];
    float* out = (float*)d_out;
    float* si = (float*)d_ws;            // B*N floats
    float* sj = si + BB * NN;            // B*N floats (128 KB total, << ws)

    score_kernel<<<(BB * NN) / 4, 256, 0, stream>>>(x, a, si, sj);
    softmax_kernel<<<BB * NN, 256, 0, stream>>>(si, sj, out);
}

// Round 2
// 52.616 us; speedup vs baseline: 1.0291x; 1.0291x over previous
//
#include <hip/hip_runtime.h>

#define BB 4
#define NN 4096
#define DD 128
#define RB 8            // rows per block (2 per wave)

// Kernel 1: per-row projections. One wave (64 lanes) per row; lane l covers
// dims l and l+64. s_i[r] = dot(x[r], a[0:128]), s_j[r] = dot(x[r], a[128:256]).
__global__ __launch_bounds__(256) void score_kernel(const float* __restrict__ x,
                                                    const float* __restrict__ a,
                                                    float* __restrict__ si,
                                                    float* __restrict__ sj) {
    int wave = threadIdx.x >> 6;
    int lane = threadIdx.x & 63;
    int row  = blockIdx.x * 4 + wave;   // grid covers B*N rows exactly
    const float* xr = x + (size_t)row * DD;
    float x0 = xr[lane];
    float x1 = xr[lane + 64];
    float d1 = x0 * a[lane]      + x1 * a[lane + 64];
    float d2 = x0 * a[DD + lane] + x1 * a[DD + lane + 64];
    #pragma unroll
    for (int off = 32; off > 0; off >>= 1) {
        d1 += __shfl_down(d1, off, 64);
        d2 += __shfl_down(d2, off, 64);
    }
    if (lane == 0) {
        si[row] = d1;
        sj[row] = d2;
    }
}

// Kernel 2: one block per RB output rows (same batch). s_j held in 64 regs
// per lane, loaded once and reused across rows. Each wave owns its rows:
// softmax sum via shfl_xor (no per-row barriers). exp recomputed in the
// write pass to keep VGPRs ~90 (occupancy for store BW).
__global__ __launch_bounds__(256) void softmax_kernel(const float* __restrict__ si_g,
                                                      const float* __restrict__ sj_g,
                                                      float* __restrict__ out) {
    __shared__ float red[4];

    const int bpb  = NN / RB;                  // 512 blocks per batch
    const int b    = blockIdx.x / bpb;
    const int i0   = (blockIdx.x % bpb) * RB;
    const int wave = threadIdx.x >> 6;
    const int lane = threadIdx.x & 63;

    // Load this batch's s_j into registers: lane l holds j = g*256 + l*4 .. +3.
    const float* sjb = sj_g + b * NN;
    float4 sjv[16];
    float lmax = -INFINITY;
    #pragma unroll
    for (int g = 0; g < 16; ++g) {
        sjv[g] = *reinterpret_cast<const float4*>(sjb + g * 256 + lane * 4);
        lmax = fmaxf(fmaxf(fmaxf(sjv[g].x, sjv[g].y), fmaxf(sjv[g].z, sjv[g].w)), lmax);
    }
    #pragma unroll
    for (int off = 1; off < 64; off <<= 1)
        lmax = fmaxf(lmax, __shfl_xor(lmax, off, 64));
    if (lane == 0) red[wave] = lmax;
    __syncthreads();
    const float sjmax = fmaxf(fmaxf(red[0], red[1]), fmaxf(red[2], red[3]));

    #pragma unroll
    for (int r = 0; r < RB / 4; ++r) {
        const int i = i0 + wave * (RB / 4) + r;
        const float sival = si_g[b * NN + i];
        // leaky_relu monotone -> row max = leaky(s_i + max_j s_j)
        float m = sival + sjmax;
        m = m > 0.f ? m : 0.2f * m;

        float lsum = 0.f;
        #pragma unroll
        for (int g = 0; g < 16; ++g) {
            float e0 = sival + sjv[g].x; e0 = (e0 > 0.f ? e0 : 0.2f * e0) - m;
            float e1 = sival + sjv[g].y; e1 = (e1 > 0.f ? e1 : 0.2f * e1) - m;
            float e2 = sival + sjv[g].z; e2 = (e2 > 0.f ? e2 : 0.2f * e2) - m;
            float e3 = sival + sjv[g].w; e3 = (e3 > 0.f ? e3 : 0.2f * e3) - m;
            lsum += __expf(e0) + __expf(e1) + __expf(e2) + __expf(e3);
        }
        #pragma unroll
        for (int off = 1; off < 64; off <<= 1)
            lsum += __shfl_xor(lsum, off, 64);
        const float inv = 1.f / lsum;

        float* orow = out + (size_t)(b * NN + i) * NN;
        #pragma unroll
        for (int g = 0; g < 16; ++g) {
            float e0 = sival + sjv[g].x; e0 = (e0 > 0.f ? e0 : 0.2f * e0) - m;
            float e1 = sival + sjv[g].y; e1 = (e1 > 0.f ? e1 : 0.2f * e1) - m;
            float e2 = sival + sjv[g].z; e2 = (e2 > 0.f ? e2 : 0.2f * e2) - m;
            float e3 = sival + sjv[g].w; e3 = (e3 > 0.f ? e3 : 0.2f * e3) - m;
            float4 v = make_float4(__expf(e0) * inv, __expf(e1) * inv,
                                   __expf(e2) * inv, __expf(e3) * inv);
            *reinterpret_cast<float4*>(orow + g * 256 + lane * 4) = v;
        }
    }
}

extern "C" void kernel_launch(void* const* d_in, const int* in_sizes, int n_in,
                              void* d_out, int out_size, void* d_ws, size_t ws_size,
                              hipStream_t stream) {
    const float* x = (const float*)d_in[0];
    const float* a = (const float*)d_in[1];
    float* out = (float*)d_out;
    float* si = (float*)d_ws;            // B*N floats
    float* sj = si + BB * NN;            // B*N floats (128 KB total, << ws)

    score_kernel<<<(BB * NN) / 4, 256, 0, stream>>>(x, a, si, sj);
    softmax_kernel<<<(BB * NN) / RB, 256, 0, stream>>>(si, sj, out);
}